// Round 9
// baseline (268.154 us; speedup 1.0000x reference)
//
#include <hip/hip_runtime.h>
#include <stdint.h>

#define BSZ 32
#define DIM 64
#define SEQ 2048
#define KE  1024

// output offsets in floats
#define O0 0ull            // quantized_st [BS][D][S]
#define O1 4194304ull      // loss (scalar)
#define O2 4194305ull      // one_hot [BS][K][S]
#define O3 71303169ull     // indices [BS][S] (as float)
#define O4 71368705ull     // distance [BS][K][S]
#define O5 138477569ull    // unquantized [BS*S][D]
#define O6 142671873ull    // embeddings.T [K][D]

// 16B store with only 4B alignment guarantee (O2/O4/O5 are odd float offsets).
struct __attribute__((packed, aligned(4))) F4 { float x, y, z, w; };

// lgkm-only barrier: global stores stay in flight across it.
__device__ __forceinline__ void lds_barrier() {
    asm volatile("s_waitcnt lgkmcnt(0)" ::: "memory");
    __builtin_amdgcn_s_barrier();
}

// async global->LDS, 16B per lane, wave-linear LDS dest.
__device__ __forceinline__ void gl_lds16(const float* g, float* l) {
    __builtin_amdgcn_global_load_lds(
        (const __attribute__((address_space(1))) uint32_t*)g,
        (__attribute__((address_space(3))) uint32_t*)l, 16, 0, 0);
}

// Kernel 0: transpose E -> out6 + aligned ws copy; b2[k] = ||e_k||^2; zero loss.
__global__ __launch_bounds__(256) void vq_prep(const float* __restrict__ E,
                                               float* __restrict__ out,
                                               float* __restrict__ et_ws,
                                               float* __restrict__ b2_ws) {
    __shared__ float T[64][65];
    const int tid  = threadIdx.x;
    const int lane = tid & 63;
    const int sub  = tid >> 6;
    const int k0   = blockIdx.x * 64;
    for (int dd = 0; dd < 16; ++dd) {
        int d = dd * 4 + sub;
        T[d][lane] = E[(size_t)d * KE + k0 + lane];
    }
    __syncthreads();
    for (int ii = 0; ii < 16; ++ii) {
        int kl = ii * 4 + sub;
        float v = T[lane][kl];
        out[O6 + (size_t)(k0 + kl) * 64 + lane] = v;
        et_ws[(size_t)(k0 + kl) * 64 + lane]    = v;
    }
    if (tid < 64) {
        float s = 0.f;
        #pragma unroll
        for (int d = 0; d < 64; ++d) {
            float v = T[d][tid];
            s = fmaf(v, v, s);
        }
        b2_ws[k0 + tid] = s;
    }
    if (blockIdx.x == 0 && tid == 0) out[O1] = 0.f;
}

// Kernel 1: distance GEMM + argmin + indices. NO one_hot / quantized here.
// grid = 32 b * 8 s-tiles = 256 blocks (1/CU); 512 thr; thread tile 8s x 16k.
// s = {sq..sq+3} u {128+sq..+3}, sq=(tid&31)*4; k = kc + (tid>>5)*16 .. +15.
// e-chunks (64x256 = 64KB) via global_load_lds, prefetched 1 chunk ahead;
// top-of-chunk vmcnt(32) retires e-loads while 32 dist stores stay in flight.
__global__ __launch_bounds__(512, 2) void vq_dist(const float* __restrict__ x,
                                                  const float* __restrict__ E,
                                                  const float* __restrict__ b2,
                                                  float* __restrict__ out) {
    __shared__ __align__(16) float xt[64 * 256];    // 64 KB x-tile [d][s]
    __shared__ __align__(16) float ebuf[64 * 256];  // 64 KB e-chunk [d][k]; reused for reduction
    __shared__ __align__(16) float a2s[256];

    const int tid = threadIdx.x;
    const int tx  = tid & 31;
    const int ky  = tid >> 5;          // 0..15
    const int b   = blockIdx.x >> 3;
    const int s0  = (blockIdx.x & 7) << 8;
    const int sq  = tx << 2;
    const int kq  = ky << 4;

    // stage x-tile + e-chunk 0 (direct to LDS; wave-linear dest, linear source)
    const float* xb = x + ((size_t)b << 17) + s0;    // D*S = 2^17
    #pragma unroll
    for (int i = 0; i < 8; ++i) {
        int f = (i << 9) + tid;          // float4 slot 0..4095
        int d = f >> 6, c4 = (f & 63) << 2;
        gl_lds16(xb + ((size_t)d << 11) + c4, &xt[(d << 8) + c4]);
    }
    #pragma unroll
    for (int i = 0; i < 8; ++i) {
        int f = (i << 9) + tid;
        int d = f >> 6, c4 = (f & 63) << 2;
        gl_lds16(E + (size_t)d * KE + c4, &ebuf[(d << 8) + c4]);
    }
    asm volatile("s_waitcnt vmcnt(0)" ::: "memory");
    __builtin_amdgcn_s_barrier();

    if (tid < 256) {
        float sacc = 0.f;
        #pragma unroll
        for (int d = 0; d < 64; ++d) { float v = xt[(d << 8) + tid]; sacc = fmaf(v, v, sacc); }
        a2s[tid] = sacc;
    }
    lds_barrier();
    float4 av0 = *(const float4*)&a2s[sq];
    float4 av1 = *(const float4*)&a2s[128 + sq];
    const float a2v[8] = {av0.x, av0.y, av0.z, av0.w, av1.x, av1.y, av1.z, av1.w};

    float bD[8]; int bK[8];
    #pragma unroll
    for (int j = 0; j < 8; ++j) { bD[j] = 3.4e38f; bK[j] = 0; }
    float* outD = out + O4 + ((size_t)b << 21) + s0;   // K*S = 2^21

    #pragma unroll 1
    for (int c = 0; c < 4; ++c) {
        const int kc = c << 8;
        if (c > 0) {
            // retire oldest (e-loads + b2) only; 32 newest dist stores keep flying
            asm volatile("s_waitcnt vmcnt(32)" ::: "memory");
            __builtin_amdgcn_s_barrier();
        }
        // b2 for this thread's k-range (issued before next e-prefetch -> older)
        float4 bb0 = *(const float4*)(b2 + kc + kq);
        float4 bb1 = *(const float4*)(b2 + kc + kq + 4);
        float4 bb2 = *(const float4*)(b2 + kc + kq + 8);
        float4 bb3 = *(const float4*)(b2 + kc + kq + 12);

        float acc[16][8];
        #pragma unroll
        for (int jk = 0; jk < 16; ++jk)
            #pragma unroll
            for (int js = 0; js < 8; ++js) acc[jk][js] = 0.f;

        #pragma unroll 2
        for (int d = 0; d < 64; ++d) {
            const float* xp = &xt[d << 8];
            const float* ep = &ebuf[(d << 8) + kq];
            float4 xa = *(const float4*)(xp + sq);          // 512B contig/wave: conflict-free
            float4 xc = *(const float4*)(xp + 128 + sq);
            float4 e0 = *(const float4*)(ep);                // 2 addrs/wave: broadcast
            float4 e1 = *(const float4*)(ep + 4);
            float4 e2 = *(const float4*)(ep + 8);
            float4 e3 = *(const float4*)(ep + 12);
            float xs[8]  = {xa.x, xa.y, xa.z, xa.w, xc.x, xc.y, xc.z, xc.w};
            float es[16] = {e0.x, e0.y, e0.z, e0.w, e1.x, e1.y, e1.z, e1.w,
                            e2.x, e2.y, e2.z, e2.w, e3.x, e3.y, e3.z, e3.w};
            #pragma unroll
            for (int jk = 0; jk < 16; ++jk)
                #pragma unroll
                for (int js = 0; js < 8; ++js)
                    acc[jk][js] = fmaf(es[jk], xs[js], acc[jk][js]);
        }
        lds_barrier();     // all waves done reading ebuf
        if (c < 3) {       // prefetch next e-chunk straight into LDS; flies under epilogue+wait
            #pragma unroll
            for (int i = 0; i < 8; ++i) {
                int f = (i << 9) + tid;
                int d = f >> 6, c4 = (f & 63) << 2;
                gl_lds16(E + (size_t)d * KE + (kc + 256) + c4, &ebuf[(d << 8) + c4]);
            }
        }
        const float b2v[16] = {bb0.x, bb0.y, bb0.z, bb0.w, bb1.x, bb1.y, bb1.z, bb1.w,
                               bb2.x, bb2.y, bb2.z, bb2.w, bb3.x, bb3.y, bb3.z, bb3.w};
        #pragma unroll
        for (int jk = 0; jk < 16; ++jk) {
            const int k = kc + kq + jk;
            float dv[8];
            #pragma unroll
            for (int js = 0; js < 8; ++js) {
                dv[js] = fmaf(-2.f, acc[jk][js], a2v[js] + b2v[jk]);
                if (dv[js] < bD[js]) { bD[js] = dv[js]; bK[js] = k; }  // k ascending -> first-min
            }
            float* pD = outD + ((size_t)k << 11);
            *(F4*)(pD + sq)       = F4{dv[0], dv[1], dv[2], dv[3]};   // 512B contig/wave-instr
            *(F4*)(pD + 128 + sq) = F4{dv[4], dv[5], dv[6], dv[7]};
        }
    }

    lds_barrier();   // ebuf reads all done; safe to reuse for reduction
    float* rD = ebuf;                     // [16 ky][256 s]
    int*   rK = (int*)(ebuf + 4096);
    #pragma unroll
    for (int js = 0; js < 8; ++js) {
        int sl = sq + (js & 3) + ((js >> 2) << 7);
        rD[(ky << 8) + sl] = bD[js];
        rK[(ky << 8) + sl] = bK[js];
    }
    __syncthreads();
    if (tid < 256) {
        float bDr = rD[tid]; int bKr = rK[tid];
        #pragma unroll
        for (int w = 1; w < 16; ++w) {
            float dw = rD[(w << 8) + tid];
            int   kw = rK[(w << 8) + tid];
            if (dw < bDr || (dw == bDr && kw < bKr)) { bDr = dw; bKr = kw; }  // global first-min
        }
        out[O3 + (size_t)b * SEQ + s0 + tid] = (float)bKr;
    }
}

// Kernel 2: pure-throughput epilogue. One thread per (b,s) column:
// one_hot column (1024 predicated stores, 256B contig per wave-instr),
// codeword gather -> quantized, unq transpose, loss partial.
// grid = 256 blocks * 256 thr = 65536 columns.
__global__ __launch_bounds__(256) void vq_post(const float* __restrict__ x,
                                               const float* __restrict__ et,
                                               float* __restrict__ out) {
    const int tid = threadIdx.x;
    const int col = (blockIdx.x << 8) + tid;    // b*2048 + s
    const int b   = col >> 11;
    const int s   = col & 2047;
    const int myk = (int)out[O3 + col];

    float* pH = out + O2 + ((size_t)b << 21) + s;
    #pragma unroll 8
    for (int k = 0; k < KE; ++k)
        pH[(size_t)k << 11] = (k == myk) ? 1.f : 0.f;

    const float* q  = et + ((size_t)myk << 6);   // L2-resident gather
    const float* xp = x + ((size_t)b << 17) + s;
    float* oq = out + ((size_t)b << 17) + s;     // O0 = 0
    float* ou = out + O5 + (size_t)col * 64;
    float lsum = 0.f;
    #pragma unroll
    for (int i = 0; i < 16; ++i) {
        float4 q4 = ((const float4*)q)[i];
        float qs[4] = {q4.x, q4.y, q4.z, q4.w};
        float xv[4];
        #pragma unroll
        for (int j = 0; j < 4; ++j) {
            int d = (i << 2) + j;
            xv[j] = xp[(size_t)d << 11];         // coalesced over s
            oq[(size_t)d << 11] = qs[j];         // coalesced over s
            float df = qs[j] - xv[j];
            lsum = fmaf(df, df, lsum);
        }
        *(F4*)(ou + (i << 2)) = F4{xv[0], xv[1], xv[2], xv[3]};  // unq row (sectors combine in L2)
    }
    #pragma unroll
    for (int m = 32; m >= 1; m >>= 1) lsum += __shfl_xor(lsum, m, 64);
    if ((tid & 63) == 0) atomicAdd(out + O1, lsum * (2.f / 4194304.f));
}

extern "C" void kernel_launch(void* const* d_in, const int* in_sizes, int n_in,
                              void* d_out, int out_size, void* d_ws, size_t ws_size,
                              hipStream_t stream) {
    const float* x = (const float*)d_in[0];
    const float* E = (const float*)d_in[1];
    float* out   = (float*)d_out;
    float* et_ws = (float*)d_ws;          // 65536 floats: E^T rows, 16B-aligned
    float* b2_ws = et_ws + 65536;         // 1024 floats
    vq_prep<<<16, 256, 0, stream>>>(E, out, et_ws, b2_ws);
    vq_dist<<<256, 512, 0, stream>>>(x, E, b2_ws, out);
    vq_post<<<256, 256, 0, stream>>>(x, et_ws, out);
}